// Round 1
// baseline (494.974 us; speedup 1.0000x reference)
//
#include <hip/hip_runtime.h>

#define B_ 4096
#define T_ 128
#define F_ 64
#define H_ 32
#define G_ 128  // 4*H

__device__ __forceinline__ float sigmoid_f(float z) {
    return __builtin_amdgcn_rcpf(1.0f + __expf(-z));
}

// One wave (64 lanes) per batch element. Lane l owns gate columns l and l+64:
//   lanes 0..31:  gA = i[j],  gB = g[j]   (j = lane)
//   lanes 32..63: gA = f[j],  gB = o[j]   (j = lane-32)
// h broadcast via per-wave LDS (write by lanes<32, read back as float4 — same-wave
// DS ops execute in order, no barrier needed; waves never share LDS regions).
extern "C" __global__ __launch_bounds__(256, 2)
void lstm_ae(const float* __restrict__ x,
             const float* __restrict__ We,
             const float* __restrict__ Ue,
             const float* __restrict__ be,
             const float* __restrict__ Wd,
             const float* __restrict__ Ud,
             const float* __restrict__ bd,
             const float* __restrict__ Wout,
             const float* __restrict__ bout,
             float* __restrict__ out)
{
    const int lane = threadIdx.x & 63;
    const int w    = threadIdx.x >> 6;
    const int b    = (blockIdx.x << 2) + w;

    __shared__ float4 xbuf4[4][2][16];  // per-wave double-buffered x row (64 floats)
    __shared__ float4 hbuf4[4][8];      // per-wave h (32 floats)
    float* hbuff = (float*)&hbuf4[w][0];

    // ---- encoder weights: register-stationary columns ----
    float weA[64], weB[64], uA[32], uB[32];
#pragma unroll
    for (int k = 0; k < 64; ++k) {
        weA[k] = We[k * G_ + lane];
        weB[k] = We[k * G_ + 64 + lane];
    }
#pragma unroll
    for (int k = 0; k < 32; ++k) {
        uA[k] = Ue[k * G_ + lane];
        uB[k] = Ue[k * G_ + 64 + lane];
    }
    const float beA = be[lane], beB = be[64 + lane];

    const float* xrow = x + (size_t)b * (T_ * F_);

    // stage x[0]; init h in LDS
    ((float*)&xbuf4[w][0][0])[lane] = xrow[lane];
    if (lane < 32) hbuff[lane] = 0.0f;

    float c = 0.0f, h = 0.0f;

    // =========================== encoder scan ===========================
#pragma unroll 1
    for (int t = 0; t < T_; ++t) {
        // prefetch next x row element (hidden behind this step's compute)
        float xnext = (t + 1 < T_) ? xrow[(t + 1) * F_ + lane] : 0.0f;

        // z = be + x@We + h@Ue  (per-lane: 2 gate columns)
        float zA0 = 0.f, zA1 = 0.f, zB0 = 0.f, zB1 = 0.f;
        const float4* xb = &xbuf4[w][t & 1][0];
#pragma unroll
        for (int q = 0; q < 16; ++q) {
            float4 xq = xb[q];
            int k = 4 * q;
            zA0 = fmaf(xq.x, weA[k + 0], zA0);
            zA1 = fmaf(xq.y, weA[k + 1], zA1);
            zA0 = fmaf(xq.z, weA[k + 2], zA0);
            zA1 = fmaf(xq.w, weA[k + 3], zA1);
            zB0 = fmaf(xq.x, weB[k + 0], zB0);
            zB1 = fmaf(xq.y, weB[k + 1], zB1);
            zB0 = fmaf(xq.z, weB[k + 2], zB0);
            zB1 = fmaf(xq.w, weB[k + 3], zB1);
        }
        float hA0 = 0.f, hA1 = 0.f, hB0 = 0.f, hB1 = 0.f;
#pragma unroll
        for (int q = 0; q < 8; ++q) {
            float4 hq = hbuf4[w][q];
            int k = 4 * q;
            hA0 = fmaf(hq.x, uA[k + 0], hA0);
            hA1 = fmaf(hq.y, uA[k + 1], hA1);
            hA0 = fmaf(hq.z, uA[k + 2], hA0);
            hA1 = fmaf(hq.w, uA[k + 3], hA1);
            hB0 = fmaf(hq.x, uB[k + 0], hB0);
            hB1 = fmaf(hq.y, uB[k + 1], hB1);
            hB0 = fmaf(hq.z, uB[k + 2], hB0);
            hB1 = fmaf(hq.w, uB[k + 3], hB1);
        }
        float zA = beA + (zA0 + zA1) + (hA0 + hA1);
        float zB = beB + (zB0 + zB1) + (hB0 + hB1);

        float sA = sigmoid_f(zA);
        float sB = sigmoid_f(zB);
        const bool lo = lane < 32;
        float aA = sA;                              // i (lo) or f (hi)
        float aB = lo ? fmaxf(zB, 0.f) : sB;        // g (lo) or o (hi)
        float pA = __shfl_xor(aA, 32, 64);
        float pB = __shfl_xor(aB, 32, 64);
        float iv = lo ? aA : pA;
        float fv = lo ? pA : aA;
        float gv = lo ? aB : pB;
        float ov = lo ? pB : aB;
        c = fmaf(fv, c, iv * gv);
        h = ov * fmaxf(c, 0.f);

        if (lane < 32) hbuff[lane] = h;                       // publish h_t
        ((float*)&xbuf4[w][(t + 1) & 1][0])[lane] = xnext;    // stage x_{t+1}
    }

    // ============ decoder constant input: zd = hT@Wd + bd (once) ============
    float zdA = bd[lane], zdB = bd[64 + lane];
#pragma unroll
    for (int q = 0; q < 8; ++q) {
        float4 hq = hbuf4[w][q];
        int k = 4 * q;
        zdA = fmaf(hq.x, Wd[(k + 0) * G_ + lane], zdA);
        zdA = fmaf(hq.y, Wd[(k + 1) * G_ + lane], zdA);
        zdA = fmaf(hq.z, Wd[(k + 2) * G_ + lane], zdA);
        zdA = fmaf(hq.w, Wd[(k + 3) * G_ + lane], zdA);
        zdB = fmaf(hq.x, Wd[(k + 0) * G_ + 64 + lane], zdB);
        zdB = fmaf(hq.y, Wd[(k + 1) * G_ + 64 + lane], zdB);
        zdB = fmaf(hq.z, Wd[(k + 2) * G_ + 64 + lane], zdB);
        zdB = fmaf(hq.w, Wd[(k + 3) * G_ + 64 + lane], zdB);
    }

    // swap weights: uA/uB <- Ud columns, weA[0:32] <- Wout column for this lane
#pragma unroll
    for (int k = 0; k < 32; ++k) {
        uA[k]  = Ud[k * G_ + lane];
        uB[k]  = Ud[k * G_ + 64 + lane];
        weA[k] = Wout[k * F_ + lane];
    }
    const float bo = bout[lane];

    float4 hreg[8];
#pragma unroll
    for (int q = 0; q < 8; ++q) hreg[q] = make_float4(0.f, 0.f, 0.f, 0.f);
    c = 0.f;

    float* orow = out + (size_t)b * (T_ * F_);

    // ================== decoder scan + fused out projection ==================
#pragma unroll 1
    for (int t = 0; t < T_; ++t) {
        float hA0 = 0.f, hA1 = 0.f, hB0 = 0.f, hB1 = 0.f;
#pragma unroll
        for (int q = 0; q < 8; ++q) {
            float4 hq = hreg[q];
            int k = 4 * q;
            hA0 = fmaf(hq.x, uA[k + 0], hA0);
            hA1 = fmaf(hq.y, uA[k + 1], hA1);
            hA0 = fmaf(hq.z, uA[k + 2], hA0);
            hA1 = fmaf(hq.w, uA[k + 3], hA1);
            hB0 = fmaf(hq.x, uB[k + 0], hB0);
            hB1 = fmaf(hq.y, uB[k + 1], hB1);
            hB0 = fmaf(hq.z, uB[k + 2], hB0);
            hB1 = fmaf(hq.w, uB[k + 3], hB1);
        }
        float zA = zdA + hA0 + hA1;
        float zB = zdB + hB0 + hB1;

        float sA = sigmoid_f(zA);
        float sB = sigmoid_f(zB);
        const bool lo = lane < 32;
        float aA = sA;
        float aB = lo ? fmaxf(zB, 0.f) : sB;
        float pA = __shfl_xor(aA, 32, 64);
        float pB = __shfl_xor(aB, 32, 64);
        float iv = lo ? aA : pA;
        float fv = lo ? pA : aA;
        float gv = lo ? aB : pB;
        float ov = lo ? pB : aB;
        c = fmaf(fv, c, iv * gv);
        h = ov * fmaxf(c, 0.f);

        if (lane < 32) hbuff[lane] = h;   // publish h_t
#pragma unroll
        for (int q = 0; q < 8; ++q) hreg[q] = hbuf4[w][q];  // full h_t to all lanes

        // out[b,t,lane] = bout[lane] + sum_j h_t[j] * Wout[j][lane]
        float o0 = bo, o1 = 0.f;
#pragma unroll
        for (int q = 0; q < 8; ++q) {
            float4 hq = hreg[q];
            int k = 4 * q;
            o0 = fmaf(hq.x, weA[k + 0], o0);
            o1 = fmaf(hq.y, weA[k + 1], o1);
            o0 = fmaf(hq.z, weA[k + 2], o0);
            o1 = fmaf(hq.w, weA[k + 3], o1);
        }
        orow[t * F_ + lane] = o0 + o1;
    }
}

extern "C" void kernel_launch(void* const* d_in, const int* in_sizes, int n_in,
                              void* d_out, int out_size, void* d_ws, size_t ws_size,
                              hipStream_t stream) {
    (void)in_sizes; (void)n_in; (void)d_ws; (void)ws_size; (void)out_size;
    const float* x    = (const float*)d_in[0];
    const float* We   = (const float*)d_in[1];
    const float* Ue   = (const float*)d_in[2];
    const float* be   = (const float*)d_in[3];
    const float* Wd   = (const float*)d_in[4];
    const float* Ud   = (const float*)d_in[5];
    const float* bd   = (const float*)d_in[6];
    const float* Wout = (const float*)d_in[7];
    const float* bout = (const float*)d_in[8];
    float* out = (float*)d_out;

    dim3 grid(B_ / 4), block(256);
    hipLaunchKernelGGL(lstm_ae, grid, block, 0, stream,
                       x, We, Ue, be, Wd, Ud, bd, Wout, bout, out);
}